// Round 12
// baseline (275.112 us; speedup 1.0000x reference)
//
#include <hip/hip_runtime.h>

typedef float f32x4  __attribute__((ext_vector_type(4)));
typedef float f32x16 __attribute__((ext_vector_type(16)));
typedef int   i32x4  __attribute__((ext_vector_type(4)));
typedef int   i32x8  __attribute__((ext_vector_type(8)));

#define AS1 __attribute__((address_space(1)))
#define AS3 __attribute__((address_space(3)))

// ---------------------------------------------------------------------------
// Kernel 1 (R1, proven): per-token quant of x -> fp8 e4m3 + scale
// ---------------------------------------------------------------------------
__global__ __launch_bounds__(256) void quant_x_fp8_kernel(
    const float* __restrict__ x, unsigned char* __restrict__ x8,
    float* __restrict__ xs, int K) {
  int m = blockIdx.x;
  int t = threadIdx.x;
  const f32x4* src = (const f32x4*)(x + (size_t)m * K + t * 16);
  f32x4 v[4];
  float am = 0.0f;
#pragma unroll
  for (int i = 0; i < 4; ++i) {
    v[i] = src[i];
#pragma unroll
    for (int j = 0; j < 4; ++j) am = fmaxf(am, __builtin_fabsf(v[i][j]));
  }
#pragma unroll
  for (int off = 32; off >= 1; off >>= 1)
    am = fmaxf(am, __shfl_xor(am, off, 64));
  __shared__ float red[4];
  int wv = t >> 6, lane = t & 63;
  if (lane == 0) red[wv] = am;
  __syncthreads();
  am = fmaxf(fmaxf(red[0], red[1]), fmaxf(red[2], red[3]));
  am = fmaxf(am, 1e-12f);
  float sc = am / 448.0f;
  if (t == 0) xs[m] = sc;
  i32x4 out;
#pragma unroll
  for (int i = 0; i < 4; ++i) {
    float q0 = v[i][0] / sc, q1 = v[i][1] / sc;
    float q2 = v[i][2] / sc, q3 = v[i][3] / sc;
    int p = __builtin_amdgcn_cvt_pk_fp8_f32(q0, q1, 0, false);
    p = __builtin_amdgcn_cvt_pk_fp8_f32(q2, q3, p, true);
    out[i] = p;
  }
  *(i32x4*)(x8 + (size_t)m * K + t * 16) = out;
}

// ---------------------------------------------------------------------------
// Kernel 2 (R1, proven): weight f32 (fp8-representable) -> fp8 bytes
// ---------------------------------------------------------------------------
__global__ __launch_bounds__(256) void quant_w_fp8_kernel(
    const float* __restrict__ w, unsigned char* __restrict__ w8) {
  size_t idx = (size_t)blockIdx.x * 256 + threadIdx.x;
  const f32x4* src = (const f32x4*)w + idx * 4;
  i32x4 out;
#pragma unroll
  for (int i = 0; i < 4; ++i) {
    f32x4 v = src[i];
    int p = __builtin_amdgcn_cvt_pk_fp8_f32(v[0], v[1], 0, false);
    p = __builtin_amdgcn_cvt_pk_fp8_f32(v[2], v[3], p, true);
    out[i] = p;
  }
  ((i32x4*)w8)[idx] = out;
}

// ---------------------------------------------------------------------------
// Kernel 3: MX-fp8 GEMM. R24 = 256-thread / 128x64 wave tile / 3-deep
// counted-vmcnt pipeline.
// R23 post-mortem: 2 blocks/CU co-resided but FLOP/cy unchanged (~2700)
// vs R20 -> independent blocks don't anti-phase; throughput is pinned by
// serial pipe-work per FLOP (m233's 2-phase stall regime). 128^2 tiles
// made LDS B/FLOP worse (7.6 vs 5.7 B/KFLOP).
// R24 exploits the allocator law (cap = 512/min-waves-per-EU; 128 at
// 512thr - R13/R14/R18): at 256 threads + (256,1) the cap is 256 ->
// the 128-VGPR acc that every 512-thr attempt spilled on now fits:
// wave tile 128(M)x64(N), acc[4][2] f32x16 = 128 + frags 48 + addr ~40
// ~= 220 <= 256. Block tile 256x128, 4 waves 2(wr)x2(wc).
// Per-wave LDS reads 24KB per 8.4MF block-tile (5.7 B/KFLOP, -25% vs
// R23); staging 48KB/tile. LDS = 3 bufs x 48KB {A 32KB, B 16KB} =
// 147456 -> 1 block/CU; stage tile T+2 in body T, counted vmcnt(12)
// (NEVER 0 in main loop) -> every load has ~2 bodies (~3000cy) cover.
// 1 barrier/tile (R17/R20-proven legality: stage(T+2)->buf (T+2)%3 =
// buf(T-1), whose ds_reads all retired before barrier(T-1): in-order
// lgkm before each wave's own MFMAs, which precede the barrier).
// vmcnt ledger: prologue stages tile0,1 (12 each), vmcnt(12) retires
// tile0. Body T stages T+2 (12) -> 24 outstanding; end-of-body
// vmcnt(12) retires T+1 before its consuming body. Tail: body KB-2
// vmcnt(0) (retire tile KB-1), body KB-1 no wait needed (vmcnt(0) noop).
// Fold (R20-validated): acc *= s_prev/s_cur in place; MFMA C-chains;
// epilogue * s_last. Swizzle (validated): 16B slot s of row r stored
// s^(r&7); inverse pre-applied on global source (rule #21); staging
// rows rIdx+32j keep row&7 == rIdx&7.
// Tripwires: VGPR ~200-230 (128 => cap law wrong); WRITE == 131072KB
// (else spill); LDS_Block 147456; Occupancy ~12.
// ---------------------------------------------------------------------------
__global__ __launch_bounds__(256, 1) void gemm_mxfp8_kernel(
    const unsigned char* __restrict__ A8,   // [M][K] fp8
    const unsigned char* __restrict__ W8,   // [N][K] fp8
    const float* __restrict__ xs,           // [M]
    const float* __restrict__ wsinv,        // [N/128][K/128]
    float* __restrict__ Y,                  // [M][N] f32
    int M, int N, int K) {
  const int KB = K >> 7;  // K/128 tiles (32)

  int bid = blockIdx.x, nwg = gridDim.x;
  int wg = (bid & 7) * (nwg >> 3) + (bid >> 3);
  int mt = M >> 8;                  // 16
  int bm = wg & (mt - 1);
  int bn = wg / mt;                 // 0..63
  int m0 = bm << 8, n0 = bn << 7;   // 256 x 128 tile

  __shared__ __align__(16) char lds[147456];  // bufs @0, @49152, @98304

  const int tid = threadIdx.x, wv = tid >> 6, lane = tid & 63;
  const int wr = wv >> 1, wc = wv & 1;          // 2 x 2 wave grid
  const int l31 = lane & 31, hi2 = lane >> 5;
  const int salt = l31 & 7;

  // per-lane slot offsets (validated swizzle)
  const int sL0 = ((hi2 * 2 + 0) ^ salt) << 4;       // ks=0, k-low 16B
  const int sH0 = ((hi2 * 2 + 1) ^ salt) << 4;       // ks=0, k-high
  const int sL1 = ((4 + hi2 * 2 + 0) ^ salt) << 4;   // ks=1
  const int sH1 = ((4 + hi2 * 2 + 1) ^ salt) << 4;

  // per-lane anchors; wave tile: A rows wr*128..+128 (mj*32 sub-blocks),
  // B rows wc*64..+64 (nj*32). Region base added at runtime (rotating int).
  const int aRow = (wr * 128 + l31) * 128;
  const int bRow = (wc * 64 + l31) * 128;
  const int aL0 = aRow + sL0, aH0 = aRow + sH0;
  const int aL1 = aRow + sL1, aH1 = aRow + sH1;
  const int bL0 = bRow + sL0, bH0 = bRow + sH0;
  const int bL1 = bRow + sL1, bH1 = bRow + sH1;

  // staging (256 thr): sweep = 32 rows (256thr x 16B = 4KB); A: 8 sweeps
  // (32KB), B: 4 sweeps (16KB). dest = region + sweep*4096 + tid*16;
  // source row = sweep*32 + (tid>>3); col pre-swizzled (involution;
  // row&7 == (tid>>3)&7 since 32 ≡ 0 mod 8).
  const int stgD = tid << 4;
  const int rIdx = tid >> 3;                 // 0..31
  const int cSrc = ((tid & 7) ^ (rIdx & 7)) << 4;
  const size_t rowB = (size_t)K;  // fp8: 1 byte/elem
  const size_t g32 = 32 * rowB;
  const char* pA = (const char*)A8 + (size_t)(m0 + rIdx) * rowB + cSrc;
  const char* pB = (const char*)W8 + (size_t)(n0 + rIdx) * rowB + cSrc;

  const float* wsv = wsinv + (size_t)bn * KB;  // N-tile 128 = one scale row

  f32x16 acc[4][2];
#pragma unroll
  for (int i = 0; i < 4; ++i)
#pragma unroll
    for (int j = 0; j < 2; ++j) acc[i][j] = (f32x16)0.0f;

  i32x8 af[2], bf[2][2];

#define GL(SRC, DST)                                                           \
  __builtin_amdgcn_global_load_lds((const AS1 void*)(SRC), (AS3 void*)(DST),   \
                                   16, 0, 0)
// A panel (256 rows, 32KB): 8 gloads
#define STG_A(COND, SB, SRC)                                                   \
  if (COND) {                                                                  \
    const char* s_ = (SRC);                                                    \
    char* d_ = lds + (SB) + stgD;                                              \
    GL(s_, d_);                                                                \
    GL(s_ + g32, d_ + 4096);                                                   \
    GL(s_ + 2 * g32, d_ + 8192);                                               \
    GL(s_ + 3 * g32, d_ + 12288);                                              \
    GL(s_ + 4 * g32, d_ + 16384);                                              \
    GL(s_ + 5 * g32, d_ + 20480);                                              \
    GL(s_ + 6 * g32, d_ + 24576);                                              \
    GL(s_ + 7 * g32, d_ + 28672);                                              \
  }
// B panel (128 rows, 16KB): 4 gloads; region at SB+32768
#define STG_B(COND, SB, SRC)                                                   \
  if (COND) {                                                                  \
    const char* s_ = (SRC);                                                    \
    char* d_ = lds + (SB) + 32768 + stgD;                                      \
    GL(s_, d_);                                                                \
    GL(s_ + g32, d_ + 4096);                                                   \
    GL(s_ + 2 * g32, d_ + 8192);                                               \
    GL(s_ + 3 * g32, d_ + 12288);                                              \
  }

// A frags for one mj (both ksteps), runtime region base RB: 4 ds_read_b128
#define RD_A(RB, MJ)                                                           \
  {                                                                            \
    const char* p_ = lds + (RB) + (MJ) * 4096;                                 \
    i32x4 lo0 = *(const i32x4*)(p_ + aL0);                                     \
    i32x4 hi0 = *(const i32x4*)(p_ + aH0);                                     \
    i32x4 lo1 = *(const i32x4*)(p_ + aL1);                                     \
    i32x4 hi1 = *(const i32x4*)(p_ + aH1);                                     \
    af[0] = __builtin_shufflevector(lo0, hi0, 0, 1, 2, 3, 4, 5, 6, 7);         \
    af[1] = __builtin_shufflevector(lo1, hi1, 0, 1, 2, 3, 4, 5, 6, 7);         \
  }
// all B frags (nj 0..1 x ks 0..1), runtime region base RB (B at +32768)
#define RD_B(RB)                                                               \
  _Pragma("unroll") for (int nj = 0; nj < 2; ++nj) {                           \
    const char* p_ = lds + (RB) + 32768 + nj * 4096;                           \
    i32x4 lo0 = *(const i32x4*)(p_ + bL0);                                     \
    i32x4 hi0 = *(const i32x4*)(p_ + bH0);                                     \
    i32x4 lo1 = *(const i32x4*)(p_ + bL1);                                     \
    i32x4 hi1 = *(const i32x4*)(p_ + bH1);                                     \
    bf[nj][0] = __builtin_shufflevector(lo0, hi0, 0, 1, 2, 3, 4, 5, 6, 7);     \
    bf[nj][1] = __builtin_shufflevector(lo1, hi1, 0, 1, 2, 3, 4, 5, 6, 7);     \
  }

// ratio-fold + chained MFMA pair for one (mj,nj); acc touched only by the
// in-place mul and as MFMA C/D (R20-validated numerics).
#define MMFn(MJ, NJ, R_)                                                       \
  {                                                                            \
    _Pragma("unroll") for (int q = 0; q < 16; ++q)                             \
        acc[MJ][NJ][q] *= (R_);                                                \
    acc[MJ][NJ] = __builtin_amdgcn_mfma_scale_f32_32x32x64_f8f6f4(             \
        af[0], bf[NJ][0], acc[MJ][NJ], 0, 0, 0, 0x7f7f7f7f, 0, 0x7f7f7f7f);    \
    acc[MJ][NJ] = __builtin_amdgcn_mfma_scale_f32_32x32x64_f8f6f4(             \
        af[1], bf[NJ][1], acc[MJ][NJ], 0, 0, 0, 0x7f7f7f7f, 0, 0x7f7f7f7f);    \
  }

  // prologue: tile0 -> buf0, tile1 -> buf1 (12 gloads each);
  // vmcnt(12) retires tile0, leaves tile1's 12 = steady invariant.
  STG_A(true, 0, pA);
  STG_B(true, 0, pB);
  STG_A(true, 49152, pA + 128);
  STG_B(true, 49152, pB + 128);
  asm volatile("s_waitcnt vmcnt(12)" ::: "memory");
  __builtin_amdgcn_s_barrier();

  int rdT = 0, stT = 98304;    // read buf of tile T; stage buf of tile T+2
  const char* pAs = pA + 256;  // stage source col of tile T+2
  const char* pBs = pB + 256;
  float sp_ = wsv[0];          // previous-tile scale (ratio = 1 at t = 0)

// body T: read+MFMA tile T from rdT; stage T+2 -> stT (issued between MFMA
// chunks); counted vmcnt; 1 barrier.
#define TILE(T, G, VM)                                                         \
  {                                                                            \
    float sc_ = wsv[(T)];                                                      \
    float r_ = sp_ / sc_;                                                      \
    RD_B(rdT);                                                                 \
    RD_A(rdT, 0);                                                              \
    __builtin_amdgcn_s_setprio(1);                                             \
    MMFn(0, 0, r_);                                                            \
    MMFn(0, 1, r_);                                                            \
    __builtin_amdgcn_s_setprio(0);                                             \
    STG_A(G, stT, pAs);                                                        \
    RD_A(rdT, 1);                                                              \
    __builtin_amdgcn_s_setprio(1);                                             \
    MMFn(1, 0, r_);                                                            \
    MMFn(1, 1, r_);                                                            \
    __builtin_amdgcn_s_setprio(0);                                             \
    STG_B(G, stT, pBs);                                                        \
    RD_A(rdT, 2);                                                              \
    __builtin_amdgcn_s_setprio(1);                                             \
    MMFn(2, 0, r_);                                                            \
    MMFn(2, 1, r_);                                                            \
    __builtin_amdgcn_s_setprio(0);                                             \
    RD_A(rdT, 3);                                                              \
    __builtin_amdgcn_s_setprio(1);                                             \
    MMFn(3, 0, r_);                                                            \
    MMFn(3, 1, r_);                                                            \
    __builtin_amdgcn_s_setprio(0);                                             \
    sp_ = sc_;                                                                 \
    asm volatile("s_waitcnt " VM ::: "memory");                                \
    __builtin_amdgcn_s_barrier();                                              \
    rdT = (rdT == 98304) ? 0 : rdT + 49152;                                    \
    stT = (stT == 98304) ? 0 : stT + 49152;                                    \
    pAs += 128;                                                                \
    pBs += 128;                                                                \
  }

#pragma unroll 1
  for (int t = 0; t < KB - 2; ++t) {
    TILE(t, true, "vmcnt(12)")
  }
  // tail: tile KB-2 (drain tile KB-1's loads), tile KB-1 (no stage).
  TILE(KB - 2, false, "vmcnt(0)")
  TILE(KB - 1, false, "vmcnt(0)")

#undef TILE
#undef MMFn
#undef RD_B
#undef RD_A
#undef STG_B
#undef STG_A
#undef GL

  // epilogue (validated C/D mapping): col=l31, row=q*8+hi2*4+j.
  // acc is in s_last domain: Y = acc * s_last * xs[row].
  const float sl_ = sp_;
#pragma unroll
  for (int mj = 0; mj < 4; ++mj)
#pragma unroll
    for (int nj = 0; nj < 2; ++nj) {
      int col = n0 + wc * 64 + nj * 32 + l31;
#pragma unroll
      for (int q = 0; q < 4; ++q) {
        int row0 = m0 + wr * 128 + mj * 32 + q * 8 + hi2 * 4;
        f32x4 sv = *(const f32x4*)(xs + row0);
#pragma unroll
        for (int j = 0; j < 4; ++j)
          Y[(size_t)(row0 + j) * N + col] = acc[mj][nj][q * 4 + j] * sv[j] * sl_;
      }
    }
}

// ---------------------------------------------------------------------------
extern "C" void kernel_launch(void* const* d_in, const int* in_sizes, int n_in,
                              void* d_out, int out_size, void* d_ws, size_t ws_size,
                              hipStream_t stream) {
  const float* x     = (const float*)d_in[0];   // [B,S,K] f32
  const float* w     = (const float*)d_in[1];   // [N,K] f32 (fp8-representable)
  const float* wsinv = (const float*)d_in[2];   // [N/128,K/128] f32
  float* y = (float*)d_out;

  const int K = 4096;
  const int M = in_sizes[0] / K;   // 4096
  const int N = in_sizes[1] / K;   // 8192

  unsigned char* x8 = (unsigned char*)d_ws;                       // M*K
  float* xs = (float*)((char*)d_ws + (size_t)M * K);              // M floats
  unsigned char* w8 =
      (unsigned char*)d_ws + (size_t)M * K + (size_t)M * 4;       // N*K

  quant_x_fp8_kernel<<<M, 256, 0, stream>>>(x, x8, xs, K);
  quant_w_fp8_kernel<<<(int)(((size_t)N * K / 16 + 255) / 256), 256, 0,
                       stream>>>(w, w8);

  dim3 grid((M / 256) * (N / 128));  // 1024
  gemm_mxfp8_kernel<<<grid, 256, 0, stream>>>(x8, w8, xs, wsinv, y, M, N, K);
}